// Round 2
// baseline (561.671 us; speedup 1.0000x reference)
//
#include <hip/hip_runtime.h>
#include <math.h>

// Problem constants
#define LSEQ   512
#define DNODE  256
#define DEDGE  128
#define NH     8
#define DHD    48
#define NQKP   4
#define NVP    8

// workspace layout (floats)
constexpr size_t N_RAW = (size_t)LSEQ*1536;      // raw projections [l][1536]
constexpr size_t N_QRO = (size_t)NH*LSEQ*DHD;    // q after rope [h][l][48]
constexpr size_t N_KT  = (size_t)NH*DHD*LSEQ;    // k after rope, transposed [h][d][m]
constexpr size_t N_VW  = (size_t)NH*LSEQ*DHD;    // v [h][m][48]
constexpr size_t N_QPW = (size_t)NH*LSEQ*12;     // q_pts [h][l][12]
constexpr size_t N_KPT = (size_t)NH*12*LSEQ;     // k_pts transposed [h][comp][m]
constexpr size_t N_VPT = (size_t)NH*LSEQ*24;     // v_pts [h][m][24]
constexpr size_t N_BIA = (size_t)NH*LSEQ*LSEQ;   // bias [h][l][m]
constexpr size_t N_PZ  = (size_t)LSEQ*LSEQ*32;   // pair_z [l][m][32]
constexpr size_t N_AW  = (size_t)NH*LSEQ*LSEQ;   // attention probs [h][l][m]
constexpr size_t N_OW  = (size_t)NH*LSEQ*DHD;    // o [h][l][48]
constexpr size_t N_OPT = (size_t)NH*LSEQ*24;     // o_pt raw [h][l][24]
constexpr size_t N_OPR = (size_t)LSEQ*256;       // o_pair [l][h*32+d]
constexpr size_t N_WT  = (size_t)40*128;         // transposed z-proj weights [o][c]

constexpr size_t OFF_RAW = 0;
constexpr size_t OFF_QRO = OFF_RAW + N_RAW;
constexpr size_t OFF_KT  = OFF_QRO + N_QRO;
constexpr size_t OFF_VW  = OFF_KT  + N_KT;
constexpr size_t OFF_QPW = OFF_VW  + N_VW;
constexpr size_t OFF_KPT = OFF_QPW + N_QPW;
constexpr size_t OFF_VPT = OFF_KPT + N_KPT;
constexpr size_t OFF_BIA = OFF_VPT + N_VPT;
constexpr size_t OFF_PZ  = OFF_BIA + N_BIA;
constexpr size_t OFF_AW  = OFF_PZ  + N_PZ;
constexpr size_t OFF_OW  = OFF_AW  + N_AW;
constexpr size_t OFF_OPT = OFF_OW  + N_OW;
constexpr size_t OFF_OPR = OFF_OPT + N_OPT;
constexpr size_t OFF_WT  = OFF_OPR + N_OPR;

// ---------------------------------------------------------------------------
// K1: node projections. Block of 256 threads handles 8 rows of s.
// Each thread computes 6 output columns (of 1536 total) for all 8 rows.
__global__ __launch_bounds__(256) void k_proj(
    const float* __restrict__ s,
    const float* __restrict__ Wq,  const float* __restrict__ bq,
    const float* __restrict__ Wkv, const float* __restrict__ bkv,
    const float* __restrict__ Wqp, const float* __restrict__ bqp,
    const float* __restrict__ Wkvp,const float* __restrict__ bkvp,
    float* __restrict__ raw)
{
    __shared__ float s_lds[8][DNODE];
    int t  = threadIdx.x;
    int l0 = blockIdx.x * 8;
    const float4* sg = (const float4*)(s + (size_t)l0*DNODE);
    float4* sl = (float4*)(&s_lds[0][0]);
    sl[t]       = sg[t];
    sl[t + 256] = sg[t + 256];
    __syncthreads();

    const float* Wp[6]; int str[6]; float bv[6];
#pragma unroll
    for (int j = 0; j < 6; j++) {
        int o = t + 256*j;
        if (o < 384)        { Wp[j] = Wq  + o;        str[j] = 384; bv[j] = bq[o]; }
        else if (o < 1152)  { Wp[j] = Wkv + (o-384);  str[j] = 768; bv[j] = bkv[o-384]; }
        else if (o < 1248)  { Wp[j] = Wqp + (o-1152); str[j] = 96;  bv[j] = bqp[o-1152]; }
        else                { Wp[j] = Wkvp+ (o-1248); str[j] = 288; bv[j] = bkvp[o-1248]; }
    }
    float acc[6][8];
#pragma unroll
    for (int j = 0; j < 6; j++)
#pragma unroll
        for (int li = 0; li < 8; li++) acc[j][li] = 0.f;

    for (int c = 0; c < DNODE; c++) {
        float sv[8];
#pragma unroll
        for (int li = 0; li < 8; li++) sv[li] = s_lds[li][c];
#pragma unroll
        for (int j = 0; j < 6; j++) {
            float w = Wp[j][c * str[j]];
#pragma unroll
            for (int li = 0; li < 8; li++) acc[j][li] += sv[li] * w;
        }
    }
#pragma unroll
    for (int j = 0; j < 6; j++) {
        int o = t + 256*j;
#pragma unroll
        for (int li = 0; li < 8; li++)
            raw[(size_t)(l0+li)*1536 + o] = acc[j][li] + bv[j];
    }
}

// ---------------------------------------------------------------------------
// K1b: per-row post-processing: RoPE(q,k), affine transform of points,
// rearrangement into attention-friendly layouts. One wave per l.
__global__ __launch_bounds__(64) void k_post(
    const float* __restrict__ raw,
    const float* __restrict__ affines,
    const int*   __restrict__ node_pos,
    float* __restrict__ qro, float* __restrict__ kt, float* __restrict__ vw,
    float* __restrict__ qpw, float* __restrict__ kpt, float* __restrict__ vpt)
{
    int l = blockIdx.x, lane = threadIdx.x;
    float rot[3][3], tr[3];
#pragma unroll
    for (int i = 0; i < 3; i++) {
#pragma unroll
        for (int j = 0; j < 3; j++) rot[i][j] = affines[l*12 + i*4 + j];
        tr[i] = affines[l*12 + i*4 + 3];
    }
    float pos = (float)node_pos[l];
    const float* r = raw + (size_t)l*1536;

    // RoPE: 192 (h,i) pairs for q, 192 for k
#pragma unroll
    for (int it = 0; it < 6; it++) {
        int pi  = lane + it*64;
        bool isq = pi < 192;
        int pk = isq ? pi : pi - 192;
        int h = pk / 24, i = pk % 24;
        float invf = powf(10000.f, -(float)i / 24.f);
        float ang = pos * invf;
        float sn, cs; sincosf(ang, &sn, &cs);
        if (isq) {
            float x1 = r[h*48 + i], x2 = r[h*48 + 24 + i];
            qro[((size_t)h*LSEQ + l)*48 + i]      = x1*cs - x2*sn;
            qro[((size_t)h*LSEQ + l)*48 + 24 + i] = x1*sn + x2*cs;
        } else {
            float x1 = r[384 + h*96 + i], x2 = r[384 + h*96 + 24 + i];
            kt[((size_t)h*48 + i)*LSEQ + l]      = x1*cs - x2*sn;
            kt[((size_t)h*48 + 24 + i)*LSEQ + l] = x1*sn + x2*cs;
        }
    }
    // v copy: 384 elements
#pragma unroll
    for (int it = 0; it < 6; it++) {
        int e = lane + it*64;
        int h = e / 48, d = e % 48;
        vw[((size_t)h*LSEQ + l)*48 + d] = r[384 + h*96 + 48 + d];
    }
    // q_pts: 32 points
    if (lane < 32) {
        int p = lane, h = p / 4, pk2 = p % 4;
        float pj[3];
#pragma unroll
        for (int j = 0; j < 3; j++) pj[j] = r[1152 + j*32 + p];
#pragma unroll
        for (int i = 0; i < 3; i++) {
            float x = rot[i][0]*pj[0] + rot[i][1]*pj[1] + rot[i][2]*pj[2] + tr[i];
            qpw[((size_t)h*LSEQ + l)*12 + pk2*3 + i] = x;
        }
    }
    // kv_pts: 96 points
#pragma unroll
    for (int it = 0; it < 2; it++) {
        int p = lane + it*64;
        if (p < 96) {
            int h = p / 12, pp = p % 12;
            float pj[3];
#pragma unroll
            for (int j = 0; j < 3; j++) pj[j] = r[1248 + j*96 + p];
#pragma unroll
            for (int i = 0; i < 3; i++) {
                float x = rot[i][0]*pj[0] + rot[i][1]*pj[1] + rot[i][2]*pj[2] + tr[i];
                if (pp < 4) kpt[((size_t)h*12 + pp*3 + i)*LSEQ + l] = x;
                else        vpt[((size_t)h*LSEQ + l)*24 + (pp-4)*3 + i] = x;
            }
        }
    }
}

// ---------------------------------------------------------------------------
// K2-prep: transpose z-projection weights into [o][c] (o<8: Wb col, else Wdown)
// so k_zproj can read them at wave-uniform addresses (scalar-load path).
__global__ __launch_bounds__(256) void k_wprep(
    const float* __restrict__ Wb, const float* __restrict__ Wdown,
    float* __restrict__ wt)
{
    int t = threadIdx.x;
#pragma unroll
    for (int i = 0; i < 20; i++) {
        int idx = t + i*256;
        int o = idx >> 7, c = idx & 127;
        wt[idx] = (o < 8) ? Wb[c*8 + o] : Wdown[c*32 + (o - 8)];
    }
}

// ---------------------------------------------------------------------------
// K2: fused z @ Wb (bias, 8 outs) and z @ Wdown (pair_z, 32 outs).
// Each wave owns 64 m-rows and ONE half (64 c) of the z rows; `half` is
// wave-uniform (readfirstlane) so weight reads scalarize to s_load.
// Wave-pairs (half 0/1) combine partials through padded LDS.
__global__ __launch_bounds__(256) void k_zproj(
    const float* __restrict__ z, const float* __restrict__ wt,
    const float* __restrict__ bb, const float* __restrict__ bdown,
    float* __restrict__ bias, float* __restrict__ pz)
{
    __shared__ float pls[2][64][41];   // stride 41: conflict-free partial dump
    int t = threadIdx.x, lane = t & 63, w = t >> 6;
    int mgroup = w >> 1;
    int half = __builtin_amdgcn_readfirstlane(w & 1);
    int l = blockIdx.y;
    int m = blockIdx.x*128 + mgroup*64 + lane;

    // this wave's half of the z row, into registers (64 floats)
    const float* zr_g = z + ((size_t)l*LSEQ + m)*DEDGE + half*64;
    float4 zr[16];
#pragma unroll
    for (int cc = 0; cc < 16; cc++) zr[cc] = ((const float4*)zr_g)[cc];

    float acc[40];
    const float* wh = wt + half*64;   // uniform base
#pragma unroll 4
    for (int o = 0; o < 40; o++) {
        const float4* wp = (const float4*)(wh + o*128);
        float a = 0.f;
#pragma unroll
        for (int cc = 0; cc < 16; cc++) {
            float4 w4 = wp[cc];       // uniform address -> scalar load
            float4 z4 = zr[cc];
            a += z4.x*w4.x + z4.y*w4.y + z4.z*w4.z + z4.w*w4.w;
        }
        acc[o] = a;
    }

    if (half == 1) {
#pragma unroll
        for (int o = 0; o < 40; o++) pls[mgroup][lane][o] = acc[o];
    }
    __syncthreads();
    if (half == 0) {
#pragma unroll
        for (int o = 0; o < 40; o++) acc[o] += pls[mgroup][lane][o];

#pragma unroll
        for (int o = 0; o < 8; o++)
            bias[((size_t)o*LSEQ + l)*LSEQ + m] = acc[o] + bb[o];
        float* pzr = pz + ((size_t)l*LSEQ + m)*32;
#pragma unroll
        for (int o = 0; o < 32; o += 4) {
            float4 v4 = make_float4(acc[8+o]   + bdown[o],
                                    acc[8+o+1] + bdown[o+1],
                                    acc[8+o+2] + bdown[o+2],
                                    acc[8+o+3] + bdown[o+3]);
            *(float4*)(pzr + o) = v4;
        }
    }
}

// ---------------------------------------------------------------------------
// K3a: logits + softmax. One wave per (h,l); each lane owns 8 m's.
__global__ __launch_bounds__(256) void k_logits(
    const float* __restrict__ qro, const float* __restrict__ kt,
    const float* __restrict__ qpw, const float* __restrict__ kpt,
    const float* __restrict__ bias, const float* __restrict__ mask,
    const float* __restrict__ head_weights,
    float* __restrict__ aw)
{
    __shared__ float qs[4][48];
    __shared__ float qps[4][12];
    int t = threadIdx.x, w = t >> 6, lane = t & 63;
    int idx = blockIdx.x*4 + w;
    int h = idx >> 9, l = idx & 511;

    if (lane < 48)      qs[w][lane]       = qro[((size_t)h*LSEQ + l)*48 + lane];
    else if (lane < 60) qps[w][lane - 48] = qpw[((size_t)h*LSEQ + l)*12 + (lane - 48)];
    __syncthreads();

    float hw = log1pf(__expf(head_weights[h])) * 0.13608276348795434f; // sqrt(1/54)
    float maskl = mask[l];

    float acc[8], d2a[8];
#pragma unroll
    for (int r2 = 0; r2 < 8; r2++) { acc[r2] = 0.f; d2a[r2] = 0.f; }

    for (int d = 0; d < 48; d++) {
        float qv = qs[w][d];
        const float* kp = kt + ((size_t)h*48 + d)*LSEQ + lane;
#pragma unroll
        for (int r2 = 0; r2 < 8; r2++) acc[r2] += qv * kp[r2*64];
    }
#pragma unroll
    for (int cmp = 0; cmp < 12; cmp++) {
        float qp = qps[w][cmp];
        const float* kp = kpt + ((size_t)h*12 + cmp)*LSEQ + lane;
#pragma unroll
        for (int r2 = 0; r2 < 8; r2++) { float df = qp - kp[r2*64]; d2a[r2] += df*df; }
    }
    float lg[8]; float mx = -1e30f;
#pragma unroll
    for (int r2 = 0; r2 < 8; r2++) {
        int m = lane + r2*64;
        float b  = bias[((size_t)h*LSEQ + l)*LSEQ + m];
        float mm = mask[m];
        lg[r2] = acc[r2]*(1.f/12.f) + 0.57735026919f*b - 0.5f*hw*d2a[r2]
               + 1000000.f*(maskl*mm - 1.f);
        mx = fmaxf(mx, lg[r2]);
    }
#pragma unroll
    for (int off = 32; off >= 1; off >>= 1) mx = fmaxf(mx, __shfl_xor(mx, off, 64));
    float sm = 0.f; float ex[8];
#pragma unroll
    for (int r2 = 0; r2 < 8; r2++) { ex[r2] = __expf(lg[r2] - mx); sm += ex[r2]; }
#pragma unroll
    for (int off = 32; off >= 1; off >>= 1) sm += __shfl_xor(sm, off, 64);
    float inv = 1.f / sm;
#pragma unroll
    for (int r2 = 0; r2 < 8; r2++)
        aw[((size_t)h*LSEQ + l)*LSEQ + lane + r2*64] = ex[r2]*inv;
}

// ---------------------------------------------------------------------------
// K3b: o = a@v, o_pt_raw = a@v_pts. One wave per (h,l); lane owns 1-2 outputs.
__global__ __launch_bounds__(256) void k_ov(
    const float* __restrict__ aw, const float* __restrict__ vw,
    const float* __restrict__ vpt,
    float* __restrict__ ow, float* __restrict__ opt)
{
    __shared__ float as[4][LSEQ];
    int t = threadIdx.x, w = t >> 6, lane = t & 63;
    int idx = blockIdx.x*4 + w;
    int h = idx >> 9, l = idx & 511;

    const float* ar = aw + ((size_t)h*LSEQ + l)*LSEQ;
#pragma unroll
    for (int r2 = 0; r2 < 8; r2++) as[w][lane + r2*64] = ar[lane + r2*64];
    __syncthreads();

    const float* p0; int s0;
    if (lane < 48) { p0 = vw  + (size_t)h*LSEQ*48 + lane;        s0 = 48; }
    else           { p0 = vpt + (size_t)h*LSEQ*24 + (lane - 48); s0 = 24; }
    int o1 = (lane < 8) ? (16 + lane) : 16;
    const float* p1 = vpt + (size_t)h*LSEQ*24 + o1;

    float acc0 = 0.f, acc1 = 0.f;
    for (int m = 0; m < LSEQ; m++) {
        float av = as[w][m];
        acc0 += av * p0[(size_t)m*s0];
        acc1 += av * p1[(size_t)m*24];
    }
    if (lane < 48) ow[((size_t)h*LSEQ + l)*48 + lane] = acc0;
    else           opt[((size_t)h*LSEQ + l)*24 + (lane - 48)] = acc0;
    if (lane < 8)  opt[((size_t)h*LSEQ + l)*24 + 16 + lane]   = acc1;
}

// ---------------------------------------------------------------------------
// K3c: o_pair = a @ pair_z per l. Block per l; thread = (h, d).
__global__ __launch_bounds__(256) void k_opair(
    const float* __restrict__ aw, const float* __restrict__ pz,
    float* __restrict__ opr)
{
    __shared__ float as[NH][LSEQ];
    int t = threadIdx.x;
    int l = blockIdx.x;
    int hh = t >> 5, mb = t & 31;
#pragma unroll
    for (int r2 = 0; r2 < 16; r2++)
        as[hh][mb + r2*32] = aw[((size_t)hh*LSEQ + l)*LSEQ + mb + r2*32];
    __syncthreads();

    int d = t & 31, h = t >> 5;
    float acc = 0.f;
    const float* pzb = pz + (size_t)l*LSEQ*32 + d;
    for (int m = 0; m < LSEQ; m++) acc += as[h][m] * pzb[(size_t)m*32];
    opr[(size_t)l*256 + t] = acc;
}

// ---------------------------------------------------------------------------
// K4: inverse point transform + norm + concat + feats @ Wout. 4 l's per block.
__global__ __launch_bounds__(256) void k_final(
    const float* __restrict__ ow, const float* __restrict__ opt,
    const float* __restrict__ opr, const float* __restrict__ affines,
    const float* __restrict__ Wout, const float* __restrict__ bout,
    float* __restrict__ out)
{
    __shared__ float fs[4][896];
    int t = threadIdx.x;
    int l0 = blockIdx.x * 4;
#pragma unroll
    for (int li = 0; li < 4; li++) {
        int l = l0 + li;
        for (int e = t; e < 384; e += 256) {
            int h = e / 48, d = e % 48;
            fs[li][e] = ow[((size_t)h*LSEQ + l)*48 + d];
        }
        if (t < 64) {
            int h = t >> 3, p = t & 7;
            const float* ob = opt + ((size_t)h*LSEQ + l)*24 + p*3;
            float r0 = ob[0], r1 = ob[1], r2v = ob[2];
            float tr0 = affines[l*12 + 3], tr1 = affines[l*12 + 7], tr2 = affines[l*12 + 11];
            float x0 = r0 - tr0, x1 = r1 - tr1, x2 = r2v - tr2;
            // out_i = sum_j rot[j][i] * x_j
            float o0 = affines[l*12+0]*x0 + affines[l*12+4]*x1 + affines[l*12+8]*x2;
            float o1 = affines[l*12+1]*x0 + affines[l*12+5]*x1 + affines[l*12+9]*x2;
            float o2 = affines[l*12+2]*x0 + affines[l*12+6]*x1 + affines[l*12+10]*x2;
            fs[li][384 + t] = o0;
            fs[li][448 + t] = o1;
            fs[li][512 + t] = o2;
            fs[li][576 + t] = sqrtf(o0*o0 + o1*o1 + o2*o2 + 1e-6f);
        }
        fs[li][640 + t] = opr[(size_t)l*256 + t];
    }
    __syncthreads();

    float acc[4];
#pragma unroll
    for (int li = 0; li < 4; li++) acc[li] = bout[t];
    for (int c = 0; c < 896; c++) {
        float wv = Wout[(size_t)c*256 + t];
#pragma unroll
        for (int li = 0; li < 4; li++) acc[li] += fs[li][c] * wv;
    }
#pragma unroll
    for (int li = 0; li < 4; li++)
        out[(size_t)(l0 + li)*256 + t] = acc[li];
}

// ---------------------------------------------------------------------------
extern "C" void kernel_launch(void* const* d_in, const int* in_sizes, int n_in,
                              void* d_out, int out_size, void* d_ws, size_t ws_size,
                              hipStream_t stream)
{
    const float* s        = (const float*)d_in[0];
    const float* z        = (const float*)d_in[1];
    const float* affines  = (const float*)d_in[2];
    const int*   node_pos = (const int*)  d_in[3];
    const float* mask     = (const float*)d_in[4];
    const float* Wq   = (const float*)d_in[5];   const float* bq   = (const float*)d_in[6];
    const float* Wkv  = (const float*)d_in[7];   const float* bkv  = (const float*)d_in[8];
    const float* Wqp  = (const float*)d_in[9];   const float* bqp  = (const float*)d_in[10];
    const float* Wkvp = (const float*)d_in[11];  const float* bkvp = (const float*)d_in[12];
    const float* Wb   = (const float*)d_in[13];  const float* bb   = (const float*)d_in[14];
    const float* Wdown= (const float*)d_in[15];  const float* bdown= (const float*)d_in[16];
    const float* head_weights = (const float*)d_in[17];
    const float* Wout = (const float*)d_in[18];  const float* bout = (const float*)d_in[19];

    float* ws  = (float*)d_ws;
    float* raw = ws + OFF_RAW;
    float* qro = ws + OFF_QRO;
    float* kt  = ws + OFF_KT;
    float* vw  = ws + OFF_VW;
    float* qpw = ws + OFF_QPW;
    float* kpt = ws + OFF_KPT;
    float* vpt = ws + OFF_VPT;
    float* bia = ws + OFF_BIA;
    float* pz  = ws + OFF_PZ;
    float* aw  = ws + OFF_AW;
    float* owp = ws + OFF_OW;
    float* opt = ws + OFF_OPT;
    float* opr = ws + OFF_OPR;
    float* wt  = ws + OFF_WT;

    k_wprep<<<1, 256, 0, stream>>>(Wb, Wdown, wt);
    k_proj<<<64, 256, 0, stream>>>(s, Wq, bq, Wkv, bkv, Wqp, bqp, Wkvp, bkvp, raw);
    k_post<<<LSEQ, 64, 0, stream>>>(raw, affines, node_pos, qro, kt, vw, qpw, kpt, vpt);
    k_zproj<<<dim3(4, LSEQ), 256, 0, stream>>>(z, wt, bb, bdown, bia, pz);
    k_logits<<<1024, 256, 0, stream>>>(qro, kt, qpw, kpt, bia, mask, head_weights, aw);
    k_ov<<<1024, 256, 0, stream>>>(aw, vw, vpt, owp, opt);
    k_opair<<<LSEQ, 256, 0, stream>>>(aw, pz, opr);
    k_final<<<128, 256, 0, stream>>>(owp, opt, opr, affines, Wout, bout, (float*)d_out);
}

// Round 6
// 517.097 us; speedup vs baseline: 1.0862x; 1.0862x over previous
//
#include <hip/hip_runtime.h>
#include <math.h>

// Problem constants
#define LSEQ   512
#define DNODE  256
#define DEDGE  128
#define NH     8
#define DHD    48
#define NQKP   4
#define NVP    8

// workspace layout (floats)
constexpr size_t N_RAW = (size_t)LSEQ*1536;      // raw projections [l][1536]
constexpr size_t N_QRO = (size_t)NH*LSEQ*DHD;    // q after rope [h][l][48]
constexpr size_t N_KT  = (size_t)NH*DHD*LSEQ;    // k after rope, transposed [h][d][m]
constexpr size_t N_VW  = (size_t)NH*LSEQ*DHD;    // v [h][m][48]
constexpr size_t N_QPW = (size_t)NH*LSEQ*12;     // q_pts [h][l][12]
constexpr size_t N_KPT = (size_t)NH*12*LSEQ;     // k_pts transposed [h][comp][m]
constexpr size_t N_VPT = (size_t)NH*LSEQ*24;     // v_pts [h][m][24]
constexpr size_t N_BIA = (size_t)NH*LSEQ*LSEQ;   // bias [h][l][m]
constexpr size_t N_PZ  = (size_t)LSEQ*LSEQ*32;   // pair_z [l][m][32]
constexpr size_t N_AW  = (size_t)NH*LSEQ*LSEQ;   // attention probs [h][l][m]
constexpr size_t N_OW  = (size_t)NH*LSEQ*DHD;    // o [h][l][48]
constexpr size_t N_OPT = (size_t)NH*LSEQ*24;     // o_pt raw [h][l][24]
constexpr size_t N_OPR = (size_t)LSEQ*256;       // o_pair [l][h*32+d]
constexpr size_t N_WT  = (size_t)40*128;         // transposed z-proj weights [o][c]

constexpr size_t OFF_RAW = 0;
constexpr size_t OFF_QRO = OFF_RAW + N_RAW;
constexpr size_t OFF_KT  = OFF_QRO + N_QRO;
constexpr size_t OFF_VW  = OFF_KT  + N_KT;
constexpr size_t OFF_QPW = OFF_VW  + N_VW;
constexpr size_t OFF_KPT = OFF_QPW + N_QPW;
constexpr size_t OFF_VPT = OFF_KPT + N_KPT;
constexpr size_t OFF_BIA = OFF_VPT + N_VPT;
constexpr size_t OFF_PZ  = OFF_BIA + N_BIA;
constexpr size_t OFF_AW  = OFF_PZ  + N_PZ;
constexpr size_t OFF_OW  = OFF_AW  + N_AW;
constexpr size_t OFF_OPT = OFF_OW  + N_OW;
constexpr size_t OFF_OPR = OFF_OPT + N_OPT;
constexpr size_t OFF_WT  = OFF_OPR + N_OPR;

// ---------------------------------------------------------------------------
// K1: node projections. Grid 768 blocks: (128 row-groups of 4) x (6 col-tiles
// of 256). One weight column per thread, 4 rows accumulated -> 4 indep FMA
// chains, unroll-8 keeps 8 weight loads in flight. Fixes the 2.9%-occupancy
// latency disaster measured in round 2 (132us, 0.25 waves/SIMD).
__global__ __launch_bounds__(256) void k_proj(
    const float* __restrict__ s,
    const float* __restrict__ Wq,  const float* __restrict__ bq,
    const float* __restrict__ Wkv, const float* __restrict__ bkv,
    const float* __restrict__ Wqp, const float* __restrict__ bqp,
    const float* __restrict__ Wkvp,const float* __restrict__ bkvp,
    float* __restrict__ raw)
{
    __shared__ float s_lds[4][DNODE];
    int t  = threadIdx.x;
    int l0 = (blockIdx.x / 6) * 4;
    int o  = (blockIdx.x % 6) * 256 + t;

    // stage 4 rows of s (4KB): 256 threads x float4
    const float4* sg = (const float4*)(s + (size_t)l0*DNODE);
    ((float4*)&s_lds[0][0])[t] = sg[t];
    __syncthreads();

    const float* Wp; int str; float bv;
    if (o < 384)       { Wp = Wq   + o;        str = 384; bv = bq[o]; }
    else if (o < 1152) { Wp = Wkv  + (o-384);  str = 768; bv = bkv[o-384]; }
    else if (o < 1248) { Wp = Wqp  + (o-1152); str = 96;  bv = bqp[o-1152]; }
    else               { Wp = Wkvp + (o-1248); str = 288; bv = bkvp[o-1248]; }

    float a0 = 0.f, a1 = 0.f, a2 = 0.f, a3 = 0.f;
#pragma unroll 8
    for (int c = 0; c < DNODE; c++) {
        float w = Wp[(size_t)c * str];
        a0 += s_lds[0][c] * w;
        a1 += s_lds[1][c] * w;
        a2 += s_lds[2][c] * w;
        a3 += s_lds[3][c] * w;
    }
    raw[(size_t)(l0+0)*1536 + o] = a0 + bv;
    raw[(size_t)(l0+1)*1536 + o] = a1 + bv;
    raw[(size_t)(l0+2)*1536 + o] = a2 + bv;
    raw[(size_t)(l0+3)*1536 + o] = a3 + bv;
}

// ---------------------------------------------------------------------------
// K1b: per-row post-processing, 4-way split over blockIdx.y to fix the
// 0.5-waves/SIMD latency bind: part 0 = q-RoPE, 1 = k-RoPE, 2 = v copy,
// 3 = point transforms. 2048 one-wave blocks = 2 waves/SIMD.
__global__ __launch_bounds__(64) void k_post(
    const float* __restrict__ raw,
    const float* __restrict__ affines,
    const int*   __restrict__ node_pos,
    float* __restrict__ qro, float* __restrict__ kt, float* __restrict__ vw,
    float* __restrict__ qpw, float* __restrict__ kpt, float* __restrict__ vpt)
{
    int l = blockIdx.x, part = blockIdx.y, lane = threadIdx.x;
    const float* r = raw + (size_t)l*1536;

    if (part == 0) {                     // q RoPE: 192 (h,i) pairs
        float pos = (float)node_pos[l];
#pragma unroll
        for (int it = 0; it < 3; it++) {
            int pk = lane + it*64;
            int h = pk / 24, i = pk % 24;
            // inv_freq = 10000^(-i/24) = 2^(-i*log2(1e4)/24)
            float ang = pos * exp2f((float)i * -0.5536546825f);
            float sn, cs; sincosf(ang, &sn, &cs);
            float x1 = r[h*48 + i], x2 = r[h*48 + 24 + i];
            qro[((size_t)h*LSEQ + l)*48 + i]      = x1*cs - x2*sn;
            qro[((size_t)h*LSEQ + l)*48 + 24 + i] = x1*sn + x2*cs;
        }
    } else if (part == 1) {              // k RoPE: 192 (h,i) pairs
        float pos = (float)node_pos[l];
#pragma unroll
        for (int it = 0; it < 3; it++) {
            int pk = lane + it*64;
            int h = pk / 24, i = pk % 24;
            float ang = pos * exp2f((float)i * -0.5536546825f);
            float sn, cs; sincosf(ang, &sn, &cs);
            float x1 = r[384 + h*96 + i], x2 = r[384 + h*96 + 24 + i];
            kt[((size_t)h*48 + i)*LSEQ + l]      = x1*cs - x2*sn;
            kt[((size_t)h*48 + 24 + i)*LSEQ + l] = x1*sn + x2*cs;
        }
    } else if (part == 2) {              // v copy: 384 elements
#pragma unroll
        for (int it = 0; it < 6; it++) {
            int e = lane + it*64;
            int h = e / 48, d = e % 48;
            vw[((size_t)h*LSEQ + l)*48 + d] = r[384 + h*96 + 48 + d];
        }
    } else {                             // point transforms
        float rot[3][3], tr[3];
#pragma unroll
        for (int i = 0; i < 3; i++) {
#pragma unroll
            for (int j = 0; j < 3; j++) rot[i][j] = affines[l*12 + i*4 + j];
            tr[i] = affines[l*12 + i*4 + 3];
        }
        if (lane < 32) {                 // q_pts: 32 points
            int p = lane, h = p / 4, pk2 = p % 4;
            float pj[3];
#pragma unroll
            for (int j = 0; j < 3; j++) pj[j] = r[1152 + j*32 + p];
#pragma unroll
            for (int i = 0; i < 3; i++) {
                float x = rot[i][0]*pj[0] + rot[i][1]*pj[1] + rot[i][2]*pj[2] + tr[i];
                qpw[((size_t)h*LSEQ + l)*12 + pk2*3 + i] = x;
            }
        }
#pragma unroll
        for (int it = 0; it < 2; it++) { // kv_pts: 96 points
            int p = lane + it*64;
            if (p < 96) {
                int h = p / 12, pp = p % 12;
                float pj[3];
#pragma unroll
                for (int j = 0; j < 3; j++) pj[j] = r[1248 + j*96 + p];
#pragma unroll
                for (int i = 0; i < 3; i++) {
                    float x = rot[i][0]*pj[0] + rot[i][1]*pj[1] + rot[i][2]*pj[2] + tr[i];
                    if (pp < 4) kpt[((size_t)h*12 + pp*3 + i)*LSEQ + l] = x;
                    else        vpt[((size_t)h*LSEQ + l)*24 + (pp-4)*3 + i] = x;
                }
            }
        }
    }
}

// ---------------------------------------------------------------------------
// K2-prep: transpose z-projection weights into [o][c] (o<8: Wb col, else Wdown)
// so k_zproj can read them at wave-uniform addresses (scalar-load path).
__global__ __launch_bounds__(256) void k_wprep(
    const float* __restrict__ Wb, const float* __restrict__ Wdown,
    float* __restrict__ wt)
{
    int t = threadIdx.x;
#pragma unroll
    for (int i = 0; i < 20; i++) {
        int idx = t + i*256;
        int o = idx >> 7, c = idx & 127;
        wt[idx] = (o < 8) ? Wb[c*8 + o] : Wdown[c*32 + (o - 8)];
    }
}

// ---------------------------------------------------------------------------
// K2: fused z @ Wb (bias, 8 outs) and z @ Wdown (pair_z, 32 outs).
// Each wave owns 64 m-rows and ONE half (64 c) of the z rows; `half` is
// wave-uniform (readfirstlane) so weight reads scalarize to s_load.
// Wave-pairs (half 0/1) combine partials through padded LDS.
__global__ __launch_bounds__(256) void k_zproj(
    const float* __restrict__ z, const float* __restrict__ wt,
    const float* __restrict__ bb, const float* __restrict__ bdown,
    float* __restrict__ bias, float* __restrict__ pz)
{
    __shared__ float pls[2][64][41];   // stride 41: conflict-free partial dump
    int t = threadIdx.x, lane = t & 63, w = t >> 6;
    int mgroup = w >> 1;
    int half = __builtin_amdgcn_readfirstlane(w & 1);
    int l = blockIdx.y;
    int m = blockIdx.x*128 + mgroup*64 + lane;

    // this wave's half of the z row, into registers (64 floats)
    const float* zr_g = z + ((size_t)l*LSEQ + m)*DEDGE + half*64;
    float4 zr[16];
#pragma unroll
    for (int cc = 0; cc < 16; cc++) zr[cc] = ((const float4*)zr_g)[cc];

    float acc[40];
    const float* wh = wt + half*64;   // uniform base
#pragma unroll 4
    for (int o = 0; o < 40; o++) {
        const float4* wp = (const float4*)(wh + o*128);
        float a = 0.f;
#pragma unroll
        for (int cc = 0; cc < 16; cc++) {
            float4 w4 = wp[cc];       // uniform address -> scalar load
            float4 z4 = zr[cc];
            a += z4.x*w4.x + z4.y*w4.y + z4.z*w4.z + z4.w*w4.w;
        }
        acc[o] = a;
    }

    if (half == 1) {
#pragma unroll
        for (int o = 0; o < 40; o++) pls[mgroup][lane][o] = acc[o];
    }
    __syncthreads();
    if (half == 0) {
#pragma unroll
        for (int o = 0; o < 40; o++) acc[o] += pls[mgroup][lane][o];

#pragma unroll
        for (int o = 0; o < 8; o++)
            bias[((size_t)o*LSEQ + l)*LSEQ + m] = acc[o] + bb[o];
        float* pzr = pz + ((size_t)l*LSEQ + m)*32;
#pragma unroll
        for (int o = 0; o < 32; o += 4) {
            float4 v4 = make_float4(acc[8+o]   + bdown[o],
                                    acc[8+o+1] + bdown[o+1],
                                    acc[8+o+2] + bdown[o+2],
                                    acc[8+o+3] + bdown[o+3]);
            *(float4*)(pzr + o) = v4;
        }
    }
}

// ---------------------------------------------------------------------------
// K3: fused logits + softmax + (a@v, a@v_pts). One wave per (h,l).
// The wave that computes the prob row keeps it in LDS (as[w]) and immediately
// contracts it against v / v_pts — saves the aw re-read and a launch vs the
// round-2 split kernels. aw is still written for k_opair (better pz locality
// there). No barrier needed: each wave writes/reads only as[w].
__global__ __launch_bounds__(256) void k_attn(
    const float* __restrict__ qro, const float* __restrict__ kt,
    const float* __restrict__ qpw, const float* __restrict__ kpt,
    const float* __restrict__ bias, const float* __restrict__ mask,
    const float* __restrict__ head_weights,
    const float* __restrict__ vw, const float* __restrict__ vpt,
    float* __restrict__ aw, float* __restrict__ ow, float* __restrict__ opt)
{
    __shared__ float as[4][LSEQ];      // prob rows, one per wave
    __shared__ float qs[4][48];
    __shared__ float qps[4][12];
    int t = threadIdx.x, w = t >> 6, lane = t & 63;
    int idx = blockIdx.x*4 + w;
    int h = idx >> 9, l = idx & 511;

    if (lane < 48)      qs[w][lane]       = qro[((size_t)h*LSEQ + l)*48 + lane];
    else if (lane < 60) qps[w][lane - 48] = qpw[((size_t)h*LSEQ + l)*12 + (lane - 48)];
    __syncthreads();

    float hw = log1pf(__expf(head_weights[h])) * 0.13608276348795434f; // sqrt(1/54)
    float maskl = mask[l];

    float acc[8], d2a[8];
#pragma unroll
    for (int r2 = 0; r2 < 8; r2++) { acc[r2] = 0.f; d2a[r2] = 0.f; }

#pragma unroll 4
    for (int d = 0; d < 48; d++) {
        float qv = qs[w][d];
        const float* kp = kt + ((size_t)h*48 + d)*LSEQ + lane;
#pragma unroll
        for (int r2 = 0; r2 < 8; r2++) acc[r2] += qv * kp[r2*64];
    }
#pragma unroll
    for (int cmp = 0; cmp < 12; cmp++) {
        float qp = qps[w][cmp];
        const float* kp = kpt + ((size_t)h*12 + cmp)*LSEQ + lane;
#pragma unroll
        for (int r2 = 0; r2 < 8; r2++) { float df = qp - kp[r2*64]; d2a[r2] += df*df; }
    }
    float lg[8]; float mx = -1e30f;
#pragma unroll
    for (int r2 = 0; r2 < 8; r2++) {
        int m = lane + r2*64;
        float b  = bias[((size_t)h*LSEQ + l)*LSEQ + m];
        float mm = mask[m];
        lg[r2] = acc[r2]*(1.f/12.f) + 0.57735026919f*b - 0.5f*hw*d2a[r2]
               + 1000000.f*(maskl*mm - 1.f);
        mx = fmaxf(mx, lg[r2]);
    }
#pragma unroll
    for (int off = 32; off >= 1; off >>= 1) mx = fmaxf(mx, __shfl_xor(mx, off, 64));
    float sm = 0.f; float ex[8];
#pragma unroll
    for (int r2 = 0; r2 < 8; r2++) { ex[r2] = __expf(lg[r2] - mx); sm += ex[r2]; }
#pragma unroll
    for (int off = 32; off >= 1; off >>= 1) sm += __shfl_xor(sm, off, 64);
    float inv = 1.f / sm;
#pragma unroll
    for (int r2 = 0; r2 < 8; r2++) {
        float p = ex[r2]*inv;
        aw[((size_t)h*LSEQ + l)*LSEQ + lane + r2*64] = p;
        as[w][lane + r2*64] = p;
    }
    // --- contraction phase (same wave consumes its own as[w] row) ---
    const float* p0; int s0;
    if (lane < 48) { p0 = vw  + (size_t)h*LSEQ*48 + lane;        s0 = 48; }
    else           { p0 = vpt + (size_t)h*LSEQ*24 + (lane - 48); s0 = 24; }
    int o1 = (lane < 8) ? (16 + lane) : 16;
    const float* p1 = vpt + (size_t)h*LSEQ*24 + o1;

    float acc0 = 0.f, acc1 = 0.f;
#pragma unroll 8
    for (int m = 0; m < LSEQ; m++) {
        float av = as[w][m];
        acc0 += av * p0[(size_t)m*s0];
        acc1 += av * p1[(size_t)m*24];
    }
    if (lane < 48) ow[((size_t)h*LSEQ + l)*48 + lane] = acc0;
    else           opt[((size_t)h*LSEQ + l)*24 + (lane - 48)] = acc0;
    if (lane < 8)  opt[((size_t)h*LSEQ + l)*24 + 16 + lane]   = acc1;
}

// ---------------------------------------------------------------------------
// K3c: o_pair = a @ pair_z per l. Block per l; thread = (h, d).
__global__ __launch_bounds__(256) void k_opair(
    const float* __restrict__ aw, const float* __restrict__ pz,
    float* __restrict__ opr)
{
    __shared__ float as[NH][LSEQ];
    int t = threadIdx.x;
    int l = blockIdx.x;
    int hh = t >> 5, mb = t & 31;
#pragma unroll
    for (int r2 = 0; r2 < 16; r2++)
        as[hh][mb + r2*32] = aw[((size_t)hh*LSEQ + l)*LSEQ + mb + r2*32];
    __syncthreads();

    int d = t & 31, h = t >> 5;
    float acc = 0.f;
    const float* pzb = pz + (size_t)l*LSEQ*32 + d;
#pragma unroll 8
    for (int m = 0; m < LSEQ; m++) acc += as[h][m] * pzb[(size_t)m*32];
    opr[(size_t)l*256 + t] = acc;
}

// ---------------------------------------------------------------------------
// K4: inverse point transform + norm + concat + feats @ Wout.
// One l per block (512 blocks) — was 4 l's per 128 blocks at 0.5 waves/SIMD.
__global__ __launch_bounds__(256) void k_final(
    const float* __restrict__ ow, const float* __restrict__ opt,
    const float* __restrict__ opr, const float* __restrict__ affines,
    const float* __restrict__ Wout, const float* __restrict__ bout,
    float* __restrict__ out)
{
    __shared__ float fs[896];
    int t = threadIdx.x;
    int l = blockIdx.x;

    for (int e = t; e < 384; e += 256) {
        int h = e / 48, d = e % 48;
        fs[e] = ow[((size_t)h*LSEQ + l)*48 + d];
    }
    if (t < 64) {
        int h = t >> 3, p = t & 7;
        const float* ob = opt + ((size_t)h*LSEQ + l)*24 + p*3;
        float r0 = ob[0], r1 = ob[1], r2v = ob[2];
        float tr0 = affines[l*12 + 3], tr1 = affines[l*12 + 7], tr2 = affines[l*12 + 11];
        float x0 = r0 - tr0, x1 = r1 - tr1, x2 = r2v - tr2;
        // out_i = sum_j rot[j][i] * x_j
        float o0 = affines[l*12+0]*x0 + affines[l*12+4]*x1 + affines[l*12+8]*x2;
        float o1 = affines[l*12+1]*x0 + affines[l*12+5]*x1 + affines[l*12+9]*x2;
        float o2 = affines[l*12+2]*x0 + affines[l*12+6]*x1 + affines[l*12+10]*x2;
        fs[384 + t] = o0;
        fs[448 + t] = o1;
        fs[512 + t] = o2;
        fs[576 + t] = sqrtf(o0*o0 + o1*o1 + o2*o2 + 1e-6f);
    }
    fs[640 + t] = opr[(size_t)l*256 + t];
    __syncthreads();

    float acc = bout[t];
#pragma unroll 8
    for (int c = 0; c < 896; c++)
        acc += fs[c] * Wout[(size_t)c*256 + t];
    out[(size_t)l*256 + t] = acc;
}

// ---------------------------------------------------------------------------
extern "C" void kernel_launch(void* const* d_in, const int* in_sizes, int n_in,
                              void* d_out, int out_size, void* d_ws, size_t ws_size,
                              hipStream_t stream)
{
    const float* s        = (const float*)d_in[0];
    const float* z        = (const float*)d_in[1];
    const float* affines  = (const float*)d_in[2];
    const int*   node_pos = (const int*)  d_in[3];
    const float* mask     = (const float*)d_in[4];
    const float* Wq   = (const float*)d_in[5];   const float* bq   = (const float*)d_in[6];
    const float* Wkv  = (const float*)d_in[7];   const float* bkv  = (const float*)d_in[8];
    const float* Wqp  = (const float*)d_in[9];   const float* bqp  = (const float*)d_in[10];
    const float* Wkvp = (const float*)d_in[11];  const float* bkvp = (const float*)d_in[12];
    const float* Wb   = (const float*)d_in[13];  const float* bb   = (const float*)d_in[14];
    const float* Wdown= (const float*)d_in[15];  const float* bdown= (const float*)d_in[16];
    const float* head_weights = (const float*)d_in[17];
    const float* Wout = (const float*)d_in[18];  const float* bout = (const float*)d_in[19];

    float* ws  = (float*)d_ws;
    float* raw = ws + OFF_RAW;
    float* qro = ws + OFF_QRO;
    float* kt  = ws + OFF_KT;
    float* vw  = ws + OFF_VW;
    float* qpw = ws + OFF_QPW;
    float* kpt = ws + OFF_KPT;
    float* vpt = ws + OFF_VPT;
    float* bia = ws + OFF_BIA;
    float* pz  = ws + OFF_PZ;
    float* aw  = ws + OFF_AW;
    float* owp = ws + OFF_OW;
    float* opt = ws + OFF_OPT;
    float* opr = ws + OFF_OPR;
    float* wt  = ws + OFF_WT;

    k_wprep<<<1, 256, 0, stream>>>(Wb, Wdown, wt);
    k_proj<<<768, 256, 0, stream>>>(s, Wq, bq, Wkv, bkv, Wqp, bqp, Wkvp, bkvp, raw);
    k_post<<<dim3(LSEQ, 4), 64, 0, stream>>>(raw, affines, node_pos, qro, kt, vw, qpw, kpt, vpt);
    k_zproj<<<dim3(4, LSEQ), 256, 0, stream>>>(z, wt, bb, bdown, bia, pz);
    k_attn<<<1024, 256, 0, stream>>>(qro, kt, qpw, kpt, bia, mask, head_weights,
                                     vw, vpt, aw, owp, opt);
    k_opair<<<LSEQ, 256, 0, stream>>>(aw, pz, opr);
    k_final<<<512, 256, 0, stream>>>(owp, opt, opr, affines, Wout, bout, (float*)d_out);
}

// Round 9
// 471.036 us; speedup vs baseline: 1.1924x; 1.0978x over previous
//
#include <hip/hip_runtime.h>
#include <math.h>

// Problem constants
#define LSEQ   512
#define DNODE  256
#define DEDGE  128
#define NH     8
#define DHD    48
#define NQKP   4
#define NVP    8

// workspace layout (floats)
constexpr size_t N_RAW = (size_t)LSEQ*1536;      // raw projections [l][1536]
constexpr size_t N_QRO = (size_t)NH*LSEQ*DHD;    // q after rope [h][l][48]
constexpr size_t N_KT  = (size_t)NH*DHD*LSEQ;    // k after rope, transposed [h][d][m]
constexpr size_t N_VW  = (size_t)NH*LSEQ*DHD;    // v [h][m][48]
constexpr size_t N_QPW = (size_t)NH*LSEQ*12;     // q_pts [h][l][12]
constexpr size_t N_KPT = (size_t)NH*12*LSEQ;     // k_pts transposed [h][comp][m]
constexpr size_t N_VPT = (size_t)NH*LSEQ*24;     // v_pts [h][m][24]
constexpr size_t N_BIA = (size_t)NH*LSEQ*LSEQ;   // bias [h][l][m]
constexpr size_t N_PZ  = (size_t)LSEQ*LSEQ*32;   // pair_z [l][m][32]
constexpr size_t N_AW  = (size_t)NH*LSEQ*LSEQ;   // attention probs [h][l][m]
constexpr size_t N_OW  = (size_t)NH*LSEQ*DHD;    // o [h][l][48]
constexpr size_t N_OPT = (size_t)NH*LSEQ*24;     // o_pt raw [h][l][24]
constexpr size_t N_OPR = (size_t)2*LSEQ*256;     // o_pair partials [2][l][h*32+d]
constexpr size_t N_WT  = (size_t)40*128;         // transposed z-proj weights [o][c]

constexpr size_t OFF_RAW = 0;
constexpr size_t OFF_QRO = OFF_RAW + N_RAW;
constexpr size_t OFF_KT  = OFF_QRO + N_QRO;
constexpr size_t OFF_VW  = OFF_KT  + N_KT;
constexpr size_t OFF_QPW = OFF_VW  + N_VW;
constexpr size_t OFF_KPT = OFF_QPW + N_QPW;
constexpr size_t OFF_VPT = OFF_KPT + N_KPT;
constexpr size_t OFF_BIA = OFF_VPT + N_VPT;
constexpr size_t OFF_PZ  = OFF_BIA + N_BIA;
constexpr size_t OFF_AW  = OFF_PZ  + N_PZ;
constexpr size_t OFF_OW  = OFF_AW  + N_AW;
constexpr size_t OFF_OPT = OFF_OW  + N_OW;
constexpr size_t OFF_OPR = OFF_OPT + N_OPT;
constexpr size_t OFF_WT  = OFF_OPR + N_OPR;

// ---------------------------------------------------------------------------
// K1: node projections. Grid 768 blocks: (128 row-groups of 4) x (6 col-tiles
// of 256). One weight column per thread, 4 rows accumulated -> 4 indep FMA
// chains, unroll-8 keeps 8 weight loads in flight.
__global__ __launch_bounds__(256) void k_proj(
    const float* __restrict__ s,
    const float* __restrict__ Wq,  const float* __restrict__ bq,
    const float* __restrict__ Wkv, const float* __restrict__ bkv,
    const float* __restrict__ Wqp, const float* __restrict__ bqp,
    const float* __restrict__ Wkvp,const float* __restrict__ bkvp,
    float* __restrict__ raw)
{
    __shared__ float s_lds[4][DNODE];
    int t  = threadIdx.x;
    int l0 = (blockIdx.x / 6) * 4;
    int o  = (blockIdx.x % 6) * 256 + t;

    const float4* sg = (const float4*)(s + (size_t)l0*DNODE);
    ((float4*)&s_lds[0][0])[t] = sg[t];
    __syncthreads();

    const float* Wp; int str; float bv;
    if (o < 384)       { Wp = Wq   + o;        str = 384; bv = bq[o]; }
    else if (o < 1152) { Wp = Wkv  + (o-384);  str = 768; bv = bkv[o-384]; }
    else if (o < 1248) { Wp = Wqp  + (o-1152); str = 96;  bv = bqp[o-1152]; }
    else               { Wp = Wkvp + (o-1248); str = 288; bv = bkvp[o-1248]; }

    float a0 = 0.f, a1 = 0.f, a2 = 0.f, a3 = 0.f;
#pragma unroll 8
    for (int c = 0; c < DNODE; c++) {
        float w = Wp[(size_t)c * str];
        a0 += s_lds[0][c] * w;
        a1 += s_lds[1][c] * w;
        a2 += s_lds[2][c] * w;
        a3 += s_lds[3][c] * w;
    }
    raw[(size_t)(l0+0)*1536 + o] = a0 + bv;
    raw[(size_t)(l0+1)*1536 + o] = a1 + bv;
    raw[(size_t)(l0+2)*1536 + o] = a2 + bv;
    raw[(size_t)(l0+3)*1536 + o] = a3 + bv;
}

// ---------------------------------------------------------------------------
// K1b: per-row post-processing, 4-way split over blockIdx.y.
__global__ __launch_bounds__(64) void k_post(
    const float* __restrict__ raw,
    const float* __restrict__ affines,
    const int*   __restrict__ node_pos,
    float* __restrict__ qro, float* __restrict__ kt, float* __restrict__ vw,
    float* __restrict__ qpw, float* __restrict__ kpt, float* __restrict__ vpt)
{
    int l = blockIdx.x, part = blockIdx.y, lane = threadIdx.x;
    const float* r = raw + (size_t)l*1536;

    if (part == 0) {                     // q RoPE: 192 (h,i) pairs
        float pos = (float)node_pos[l];
#pragma unroll
        for (int it = 0; it < 3; it++) {
            int pk = lane + it*64;
            int h = pk / 24, i = pk % 24;
            float ang = pos * exp2f((float)i * -0.5536546825f);
            float sn, cs; sincosf(ang, &sn, &cs);
            float x1 = r[h*48 + i], x2 = r[h*48 + 24 + i];
            qro[((size_t)h*LSEQ + l)*48 + i]      = x1*cs - x2*sn;
            qro[((size_t)h*LSEQ + l)*48 + 24 + i] = x1*sn + x2*cs;
        }
    } else if (part == 1) {              // k RoPE: 192 (h,i) pairs
        float pos = (float)node_pos[l];
#pragma unroll
        for (int it = 0; it < 3; it++) {
            int pk = lane + it*64;
            int h = pk / 24, i = pk % 24;
            float ang = pos * exp2f((float)i * -0.5536546825f);
            float sn, cs; sincosf(ang, &sn, &cs);
            float x1 = r[384 + h*96 + i], x2 = r[384 + h*96 + 24 + i];
            kt[((size_t)h*48 + i)*LSEQ + l]      = x1*cs - x2*sn;
            kt[((size_t)h*48 + 24 + i)*LSEQ + l] = x1*sn + x2*cs;
        }
    } else if (part == 2) {              // v copy: 384 elements
#pragma unroll
        for (int it = 0; it < 6; it++) {
            int e = lane + it*64;
            int h = e / 48, d = e % 48;
            vw[((size_t)h*LSEQ + l)*48 + d] = r[384 + h*96 + 48 + d];
        }
    } else {                             // point transforms
        float rot[3][3], tr[3];
#pragma unroll
        for (int i = 0; i < 3; i++) {
#pragma unroll
            for (int j = 0; j < 3; j++) rot[i][j] = affines[l*12 + i*4 + j];
            tr[i] = affines[l*12 + i*4 + 3];
        }
        if (lane < 32) {                 // q_pts: 32 points
            int p = lane, h = p / 4, pk2 = p % 4;
            float pj[3];
#pragma unroll
            for (int j = 0; j < 3; j++) pj[j] = r[1152 + j*32 + p];
#pragma unroll
            for (int i = 0; i < 3; i++) {
                float x = rot[i][0]*pj[0] + rot[i][1]*pj[1] + rot[i][2]*pj[2] + tr[i];
                qpw[((size_t)h*LSEQ + l)*12 + pk2*3 + i] = x;
            }
        }
#pragma unroll
        for (int it = 0; it < 2; it++) { // kv_pts: 96 points
            int p = lane + it*64;
            if (p < 96) {
                int h = p / 12, pp = p % 12;
                float pj[3];
#pragma unroll
                for (int j = 0; j < 3; j++) pj[j] = r[1248 + j*96 + p];
#pragma unroll
                for (int i = 0; i < 3; i++) {
                    float x = rot[i][0]*pj[0] + rot[i][1]*pj[1] + rot[i][2]*pj[2] + tr[i];
                    if (pp < 4) kpt[((size_t)h*12 + pp*3 + i)*LSEQ + l] = x;
                    else        vpt[((size_t)h*LSEQ + l)*24 + (pp-4)*3 + i] = x;
                }
            }
        }
    }
}

// ---------------------------------------------------------------------------
// K2-prep: transpose z-projection weights into [o][c] (o<8: Wb col, else Wdown).
__global__ __launch_bounds__(256) void k_wprep(
    const float* __restrict__ Wb, const float* __restrict__ Wdown,
    float* __restrict__ wt)
{
    int t = threadIdx.x;
#pragma unroll
    for (int i = 0; i < 20; i++) {
        int idx = t + i*256;
        int o = idx >> 7, c = idx & 127;
        wt[idx] = (o < 8) ? Wb[c*8 + o] : Wdown[c*32 + (o - 8)];
    }
}

// ---------------------------------------------------------------------------
// K2: fused z @ Wb (bias, 8 outs) and z @ Wdown (pair_z, 32 outs).
// LDS-tiled GEMM: z tile [64 rows][128K] (padded to 132 -> <=4-way bank
// aliasing on reads) + full weight table [40][128] in LDS. Thread (og,mg)
// owns rows {mg, mg+32} x outs {og*5..og*5+4}; K consumed as float4.
// Round-6 PMC showed the old "z in regs + scalar weights" design was
// compiler-demoted (VGPR 72 -> z reloaded from L2; 118us, 19% VALU).
__global__ __launch_bounds__(256) void k_zproj(
    const float* __restrict__ z, const float* __restrict__ wt,
    const float* __restrict__ bb, const float* __restrict__ bdown,
    float* __restrict__ bias, float* __restrict__ pz)
{
    __shared__ float zt[64][132];      // 33792 B
    __shared__ float wl[40][128];      // 20480 B
    int t = threadIdx.x;
    int l = blockIdx.y;
    int m0 = blockIdx.x * 64;

    // stage z tile: 64 rows x 32 float4, coalesced
    const float4* zg = (const float4*)(z + ((size_t)l*LSEQ + m0)*DEDGE);
#pragma unroll
    for (int i = 0; i < 8; i++) {
        int idx = t + i*256;
        int row = idx >> 5, c4 = idx & 31;
        *(float4*)&zt[row][c4*4] = zg[idx];
    }
    // stage weights: 40 rows x 32 float4
    const float4* wg = (const float4*)wt;
#pragma unroll
    for (int i = 0; i < 5; i++) {
        int idx = t + i*256;
        int o = idx >> 5, c4 = idx & 31;
        *(float4*)&wl[o][c4*4] = wg[idx];
    }
    __syncthreads();

    int og = t >> 5;          // 0..7 (5 outs each)
    int mg = t & 31;          // rows mg, mg+32

    float acc0[5], acc1[5];
#pragma unroll
    for (int j = 0; j < 5; j++) { acc0[j] = 0.f; acc1[j] = 0.f; }

#pragma unroll 4
    for (int k4 = 0; k4 < 32; k4++) {
        float4 z0 = *(const float4*)&zt[mg][k4*4];
        float4 z1 = *(const float4*)&zt[mg+32][k4*4];
#pragma unroll
        for (int j = 0; j < 5; j++) {
            float4 w4 = *(const float4*)&wl[og*5+j][k4*4];   // broadcast (free)
            acc0[j] += z0.x*w4.x + z0.y*w4.y + z0.z*w4.z + z0.w*w4.w;
            acc1[j] += z1.x*w4.x + z1.y*w4.y + z1.z*w4.z + z1.w*w4.w;
        }
    }

#pragma unroll
    for (int j = 0; j < 5; j++) {
        int o = og*5 + j;
        if (o < 8) {
            float b = bb[o];
            bias[((size_t)o*LSEQ + l)*LSEQ + m0 + mg]      = acc0[j] + b;
            bias[((size_t)o*LSEQ + l)*LSEQ + m0 + mg + 32] = acc1[j] + b;
        } else {
            float b = bdown[o-8];
            pz[((size_t)l*LSEQ + m0 + mg)*32      + (o-8)] = acc0[j] + b;
            pz[((size_t)l*LSEQ + m0 + mg + 32)*32 + (o-8)] = acc1[j] + b;
        }
    }
}

// ---------------------------------------------------------------------------
// K3: fused logits + softmax + (a@v, a@v_pts). One wave per (h,l).
__global__ __launch_bounds__(256) void k_attn(
    const float* __restrict__ qro, const float* __restrict__ kt,
    const float* __restrict__ qpw, const float* __restrict__ kpt,
    const float* __restrict__ bias, const float* __restrict__ mask,
    const float* __restrict__ head_weights,
    const float* __restrict__ vw, const float* __restrict__ vpt,
    float* __restrict__ aw, float* __restrict__ ow, float* __restrict__ opt)
{
    __shared__ float as[4][LSEQ];      // prob rows, one per wave
    __shared__ float qs[4][48];
    __shared__ float qps[4][12];
    int t = threadIdx.x, w = t >> 6, lane = t & 63;
    int idx = blockIdx.x*4 + w;
    int h = idx >> 9, l = idx & 511;

    if (lane < 48)      qs[w][lane]       = qro[((size_t)h*LSEQ + l)*48 + lane];
    else if (lane < 60) qps[w][lane - 48] = qpw[((size_t)h*LSEQ + l)*12 + (lane - 48)];
    __syncthreads();

    float hw = log1pf(__expf(head_weights[h])) * 0.13608276348795434f; // sqrt(1/54)
    float maskl = mask[l];

    float acc[8], d2a[8];
#pragma unroll
    for (int r2 = 0; r2 < 8; r2++) { acc[r2] = 0.f; d2a[r2] = 0.f; }

#pragma unroll 4
    for (int d = 0; d < 48; d++) {
        float qv = qs[w][d];
        const float* kp = kt + ((size_t)h*48 + d)*LSEQ + lane;
#pragma unroll
        for (int r2 = 0; r2 < 8; r2++) acc[r2] += qv * kp[r2*64];
    }
#pragma unroll
    for (int cmp = 0; cmp < 12; cmp++) {
        float qp = qps[w][cmp];
        const float* kp = kpt + ((size_t)h*12 + cmp)*LSEQ + lane;
#pragma unroll
        for (int r2 = 0; r2 < 8; r2++) { float df = qp - kp[r2*64]; d2a[r2] += df*df; }
    }
    float lg[8]; float mx = -1e30f;
#pragma unroll
    for (int r2 = 0; r2 < 8; r2++) {
        int m = lane + r2*64;
        float b  = bias[((size_t)h*LSEQ + l)*LSEQ + m];
        float mm = mask[m];
        lg[r2] = acc[r2]*(1.f/12.f) + 0.57735026919f*b - 0.5f*hw*d2a[r2]
               + 1000000.f*(maskl*mm - 1.f);
        mx = fmaxf(mx, lg[r2]);
    }
#pragma unroll
    for (int off = 32; off >= 1; off >>= 1) mx = fmaxf(mx, __shfl_xor(mx, off, 64));
    float sm = 0.f; float ex[8];
#pragma unroll
    for (int r2 = 0; r2 < 8; r2++) { ex[r2] = __expf(lg[r2] - mx); sm += ex[r2]; }
#pragma unroll
    for (int off = 32; off >= 1; off >>= 1) sm += __shfl_xor(sm, off, 64);
    float inv = 1.f / sm;
#pragma unroll
    for (int r2 = 0; r2 < 8; r2++) {
        float p = ex[r2]*inv;
        aw[((size_t)h*LSEQ + l)*LSEQ + lane + r2*64] = p;
        as[w][lane + r2*64] = p;
    }
    // --- contraction phase (same wave consumes its own as[w] row) ---
    const float* p0; int s0;
    if (lane < 48) { p0 = vw  + (size_t)h*LSEQ*48 + lane;        s0 = 48; }
    else           { p0 = vpt + (size_t)h*LSEQ*24 + (lane - 48); s0 = 24; }
    int o1 = (lane < 8) ? (16 + lane) : 16;
    const float* p1 = vpt + (size_t)h*LSEQ*24 + o1;

    float acc0 = 0.f, acc1 = 0.f;
#pragma unroll 8
    for (int m = 0; m < LSEQ; m++) {
        float av = as[w][m];
        acc0 += av * p0[(size_t)m*s0];
        acc1 += av * p1[(size_t)m*24];
    }
    if (lane < 48) ow[((size_t)h*LSEQ + l)*48 + lane] = acc0;
    else           opt[((size_t)h*LSEQ + l)*24 + (lane - 48)] = acc0;
    if (lane < 8)  opt[((size_t)h*LSEQ + l)*24 + 16 + lane]   = acc1;
}

// ---------------------------------------------------------------------------
// K3c: o_pair = a @ pair_z. 2-way m-split (blockIdx.y) for 2x waves and half
// the serial trip count; partials summed in k_final.
__global__ __launch_bounds__(256) void k_opair(
    const float* __restrict__ aw, const float* __restrict__ pz,
    float* __restrict__ opr)
{
    __shared__ float as[NH][256];
    int t = threadIdx.x;
    int l = blockIdx.x;
    int part = blockIdx.y;
    int mbase = part*256;
    int hh = t >> 5, mb = t & 31;
#pragma unroll
    for (int r2 = 0; r2 < 8; r2++)
        as[hh][mb + r2*32] = aw[((size_t)hh*LSEQ + l)*LSEQ + mbase + mb + r2*32];
    __syncthreads();

    int d = t & 31, h = t >> 5;
    float acc = 0.f;
    const float* pzb = pz + ((size_t)l*LSEQ + mbase)*32 + d;
#pragma unroll 8
    for (int m = 0; m < 256; m++) acc += as[h][m] * pzb[(size_t)m*32];
    opr[(size_t)part*LSEQ*256 + (size_t)l*256 + t] = acc;
}

// ---------------------------------------------------------------------------
// K4: inverse point transform + norm + concat + feats @ Wout. One l per block.
__global__ __launch_bounds__(256) void k_final(
    const float* __restrict__ ow, const float* __restrict__ opt,
    const float* __restrict__ opr, const float* __restrict__ affines,
    const float* __restrict__ Wout, const float* __restrict__ bout,
    float* __restrict__ out)
{
    __shared__ float fs[896];
    int t = threadIdx.x;
    int l = blockIdx.x;

    for (int e = t; e < 384; e += 256) {
        int h = e / 48, d = e % 48;
        fs[e] = ow[((size_t)h*LSEQ + l)*48 + d];
    }
    if (t < 64) {
        int h = t >> 3, p = t & 7;
        const float* ob = opt + ((size_t)h*LSEQ + l)*24 + p*3;
        float r0 = ob[0], r1 = ob[1], r2v = ob[2];
        float tr0 = affines[l*12 + 3], tr1 = affines[l*12 + 7], tr2 = affines[l*12 + 11];
        float x0 = r0 - tr0, x1 = r1 - tr1, x2 = r2v - tr2;
        float o0 = affines[l*12+0]*x0 + affines[l*12+4]*x1 + affines[l*12+8]*x2;
        float o1 = affines[l*12+1]*x0 + affines[l*12+5]*x1 + affines[l*12+9]*x2;
        float o2 = affines[l*12+2]*x0 + affines[l*12+6]*x1 + affines[l*12+10]*x2;
        fs[384 + t] = o0;
        fs[448 + t] = o1;
        fs[512 + t] = o2;
        fs[576 + t] = sqrtf(o0*o0 + o1*o1 + o2*o2 + 1e-6f);
    }
    fs[640 + t] = opr[(size_t)l*256 + t] + opr[(size_t)LSEQ*256 + (size_t)l*256 + t];
    __syncthreads();

    float acc = bout[t];
#pragma unroll 8
    for (int c = 0; c < 896; c++)
        acc += fs[c] * Wout[(size_t)c*256 + t];
    out[(size_t)l*256 + t] = acc;
}

// ---------------------------------------------------------------------------
extern "C" void kernel_launch(void* const* d_in, const int* in_sizes, int n_in,
                              void* d_out, int out_size, void* d_ws, size_t ws_size,
                              hipStream_t stream)
{
    const float* s        = (const float*)d_in[0];
    const float* z        = (const float*)d_in[1];
    const float* affines  = (const float*)d_in[2];
    const int*   node_pos = (const int*)  d_in[3];
    const float* mask     = (const float*)d_in[4];
    const float* Wq   = (const float*)d_in[5];   const float* bq   = (const float*)d_in[6];
    const float* Wkv  = (const float*)d_in[7];   const float* bkv  = (const float*)d_in[8];
    const float* Wqp  = (const float*)d_in[9];   const float* bqp  = (const float*)d_in[10];
    const float* Wkvp = (const float*)d_in[11];  const float* bkvp = (const float*)d_in[12];
    const float* Wb   = (const float*)d_in[13];  const float* bb   = (const float*)d_in[14];
    const float* Wdown= (const float*)d_in[15];  const float* bdown= (const float*)d_in[16];
    const float* head_weights = (const float*)d_in[17];
    const float* Wout = (const float*)d_in[18];  const float* bout = (const float*)d_in[19];

    float* ws  = (float*)d_ws;
    float* raw = ws + OFF_RAW;
    float* qro = ws + OFF_QRO;
    float* kt  = ws + OFF_KT;
    float* vw  = ws + OFF_VW;
    float* qpw = ws + OFF_QPW;
    float* kpt = ws + OFF_KPT;
    float* vpt = ws + OFF_VPT;
    float* bia = ws + OFF_BIA;
    float* pz  = ws + OFF_PZ;
    float* aw  = ws + OFF_AW;
    float* owp = ws + OFF_OW;
    float* opt = ws + OFF_OPT;
    float* opr = ws + OFF_OPR;
    float* wt  = ws + OFF_WT;

    k_wprep<<<1, 256, 0, stream>>>(Wb, Wdown, wt);
    k_proj<<<768, 256, 0, stream>>>(s, Wq, bq, Wkv, bkv, Wqp, bqp, Wkvp, bkvp, raw);
    k_post<<<dim3(LSEQ, 4), 64, 0, stream>>>(raw, affines, node_pos, qro, kt, vw, qpw, kpt, vpt);
    k_zproj<<<dim3(8, LSEQ), 256, 0, stream>>>(z, wt, bb, bdown, bia, pz);
    k_attn<<<1024, 256, 0, stream>>>(qro, kt, qpw, kpt, bia, mask, head_weights,
                                     vw, vpt, aw, owp, opt);
    k_opair<<<dim3(LSEQ, 2), 256, 0, stream>>>(aw, pz, opr);
    k_final<<<512, 256, 0, stream>>>(owp, opt, opr, affines, Wout, bout, (float*)d_out);
}